// Round 1
// baseline (155.291 us; speedup 1.0000x reference)
//
#include <hip/hip_runtime.h>
#include <hip/hip_bf16.h>

typedef __attribute__((ext_vector_type(8))) short short8;
typedef __attribute__((ext_vector_type(4))) float floatx4;

#define NSEQ 8
#define LQ_TOK 256
#define BLKSZ 16
#define NBLK_PER_SEQ 128
#define HQN 32
#define HKVN 8
#define GQ 4
#define HD 128
#define WINDOW 1024
#define SCALE 0.08838834764831845f

#define QB 32        // q rows per wave (per GQA head)
#define KVB 32       // kv tile size
#define KROW 136     // K lds row stride (bf16 elems): 128 + 8 pad
#define VROW 40      // V^T lds row stride: 32 + 8 pad
#define PROW 40      // P lds row stride: 32 + 8 pad

static __device__ __forceinline__ short f2bf(float x) {
    unsigned int u = __builtin_bit_cast(unsigned int, x);
    u += 0x7FFFu + ((u >> 16) & 1u);   // RNE
    return (short)(u >> 16);
}

#define MFMA16 __builtin_amdgcn_mfma_f32_16x16x32_bf16

__global__ __launch_bounds__(256, 2)
void attn_fwd(const float* __restrict__ qg,
              const float* __restrict__ kg,
              const float* __restrict__ vg,
              const int* __restrict__ bt,
              const int* __restrict__ seqlens,
              const int* __restrict__ qsl,
              float* __restrict__ outg)
{
    __shared__ __align__(16) short Klds[KVB][KROW];
    __shared__ __align__(16) short Vt[HD][VROW];
    __shared__ __align__(16) short Plds[4][QB][PROW];

    const int tid  = threadIdx.x;
    const int wave = tid >> 6;
    const int lane = tid & 63;
    const int l15  = lane & 15;
    const int lg   = lane >> 4;      // 0..3

    const int qt = blockIdx.x;       // q tile within seq (0..7)
    const int h  = blockIdx.y;       // kv head
    const int s  = blockIdx.z;       // sequence
    const int g  = wave;             // GQA sub-head
    const int q0 = qt * QB;

    const int qstart = qsl[s];
    const int numq   = qsl[s + 1] - qstart;   // 256
    const int slen   = seqlens[s];            // 2048
    const int ctx    = slen - numq;           // 1792
    const int hq     = h * GQ + g;

    // ---- Q fragments in registers: qf[mt][kt], A-layout ----
    short8 qf[2][4];
    #pragma unroll
    for (int mt = 0; mt < 2; ++mt) {
        const float* qrow = qg + ((size_t)(qstart + q0 + mt * 16 + l15) * HQN + hq) * HD;
        #pragma unroll
        for (int kt = 0; kt < 4; ++kt) {
            const float* p0 = qrow + kt * 32 + lg * 8;
            floatx4 f0 = *(const floatx4*)p0;
            floatx4 f1 = *(const floatx4*)(p0 + 4);
            short8 v;
            v[0] = f2bf(f0[0]); v[1] = f2bf(f0[1]); v[2] = f2bf(f0[2]); v[3] = f2bf(f0[3]);
            v[4] = f2bf(f1[0]); v[5] = f2bf(f1[1]); v[6] = f2bf(f1[2]); v[7] = f2bf(f1[3]);
            qf[mt][kt] = v;
        }
    }

    floatx4 oacc[2][8];
    #pragma unroll
    for (int mt = 0; mt < 2; ++mt)
        #pragma unroll
        for (int n = 0; n < 8; ++n)
            oacc[mt][n] = (floatx4){0.f, 0.f, 0.f, 0.f};

    float mrun[2][4], lrun[2][4];
    #pragma unroll
    for (int mt = 0; mt < 2; ++mt)
        #pragma unroll
        for (int r = 0; r < 4; ++r) { mrun[mt][r] = -INFINITY; lrun[mt][r] = 0.f; }

    // sliding-window kv range for this q tile
    int lo = ctx + q0 - WINDOW + 1; if (lo < 0) lo = 0;
    int hi = ctx + q0 + QB - 1;     if (hi > slen - 1) hi = slen - 1;
    const int t0 = lo / KVB, t1 = hi / KVB;

    const int srow = tid >> 3;          // 0..31 (kv row for staging)
    const int sd0  = (tid & 7) * 16;    // 0..112 (d offset for staging)

    for (int t = t0; t <= t1; ++t) {
        const int kv0 = t * KVB;
        __syncthreads();   // previous tile's compute done before overwrite
        // ---- stage K tile and V^T tile (fp32 -> bf16) ----
        {
            int p   = kv0 + srow;
            int blk = bt[s * NBLK_PER_SEQ + (p >> 4)];
            size_t base = (((size_t)blk * BLKSZ + (p & 15)) * HKVN + h) * HD + sd0;
            const float* krow = kg + base;
            const float* vrow = vg + base;
            floatx4 a0 = *(const floatx4*)(krow + 0);
            floatx4 a1 = *(const floatx4*)(krow + 4);
            floatx4 a2 = *(const floatx4*)(krow + 8);
            floatx4 a3 = *(const floatx4*)(krow + 12);
            short8 w0, w1;
            w0[0] = f2bf(a0[0]); w0[1] = f2bf(a0[1]); w0[2] = f2bf(a0[2]); w0[3] = f2bf(a0[3]);
            w0[4] = f2bf(a1[0]); w0[5] = f2bf(a1[1]); w0[6] = f2bf(a1[2]); w0[7] = f2bf(a1[3]);
            w1[0] = f2bf(a2[0]); w1[1] = f2bf(a2[1]); w1[2] = f2bf(a2[2]); w1[3] = f2bf(a2[3]);
            w1[4] = f2bf(a3[0]); w1[5] = f2bf(a3[1]); w1[6] = f2bf(a3[2]); w1[7] = f2bf(a3[3]);
            *(short8*)&Klds[srow][sd0]     = w0;
            *(short8*)&Klds[srow][sd0 + 8] = w1;
            floatx4 b0 = *(const floatx4*)(vrow + 0);
            floatx4 b1 = *(const floatx4*)(vrow + 4);
            floatx4 b2 = *(const floatx4*)(vrow + 8);
            floatx4 b3 = *(const floatx4*)(vrow + 12);
            #pragma unroll
            for (int i = 0; i < 4; ++i) {
                Vt[sd0 + i     ][srow] = f2bf(b0[i]);
                Vt[sd0 + 4 + i ][srow] = f2bf(b1[i]);
                Vt[sd0 + 8 + i ][srow] = f2bf(b2[i]);
                Vt[sd0 + 12 + i][srow] = f2bf(b3[i]);
            }
        }
        __syncthreads();

        // ---- QK^T ----
        floatx4 sacc[2][2];
        sacc[0][0] = (floatx4){0.f,0.f,0.f,0.f}; sacc[0][1] = (floatx4){0.f,0.f,0.f,0.f};
        sacc[1][0] = (floatx4){0.f,0.f,0.f,0.f}; sacc[1][1] = (floatx4){0.f,0.f,0.f,0.f};
        #pragma unroll
        for (int kt = 0; kt < 4; ++kt) {
            short8 kf0 = *(const short8*)&Klds[l15     ][kt * 32 + lg * 8];
            short8 kf1 = *(const short8*)&Klds[16 + l15][kt * 32 + lg * 8];
            sacc[0][0] = MFMA16(qf[0][kt], kf0, sacc[0][0], 0, 0, 0);
            sacc[0][1] = MFMA16(qf[0][kt], kf1, sacc[0][1], 0, 0, 0);
            sacc[1][0] = MFMA16(qf[1][kt], kf0, sacc[1][0], 0, 0, 0);
            sacc[1][1] = MFMA16(qf[1][kt], kf1, sacc[1][1], 0, 0, 0);
        }

        // ---- online softmax (rows live across 16-lane groups) ----
        #pragma unroll
        for (int mt = 0; mt < 2; ++mt) {
            #pragma unroll
            for (int r = 0; r < 4; ++r) {
                const int qpos = ctx + q0 + mt * 16 + lg * 4 + r;
                float sv0, sv1;
                {
                    int kpos = kv0 + l15;
                    bool valid = (kpos <= qpos) && (qpos - kpos < WINDOW);
                    sv0 = valid ? sacc[mt][0][r] * SCALE : -INFINITY;
                }
                {
                    int kpos = kv0 + 16 + l15;
                    bool valid = (kpos <= qpos) && (qpos - kpos < WINDOW);
                    sv1 = valid ? sacc[mt][1][r] * SCALE : -INFINITY;
                }
                float rmax = fmaxf(sv0, sv1);
                rmax = fmaxf(rmax, __shfl_xor(rmax, 1));
                rmax = fmaxf(rmax, __shfl_xor(rmax, 2));
                rmax = fmaxf(rmax, __shfl_xor(rmax, 4));
                rmax = fmaxf(rmax, __shfl_xor(rmax, 8));
                float mold = mrun[mt][r];
                float mnew = fmaxf(mold, rmax);
                bool dead = (mnew == -INFINITY);
                float alpha = dead ? 1.0f : __expf(mold - mnew);  // mold=-inf -> 0
                float p0 = dead ? 0.0f : __expf(sv0 - mnew);      // sv=-inf -> 0
                float p1 = dead ? 0.0f : __expf(sv1 - mnew);
                float rsum = p0 + p1;
                rsum += __shfl_xor(rsum, 1);
                rsum += __shfl_xor(rsum, 2);
                rsum += __shfl_xor(rsum, 4);
                rsum += __shfl_xor(rsum, 8);
                lrun[mt][r] = lrun[mt][r] * alpha + rsum;
                mrun[mt][r] = mnew;
                #pragma unroll
                for (int n = 0; n < 8; ++n) oacc[mt][n][r] *= alpha;
                const int prow = mt * 16 + lg * 4 + r;
                Plds[wave][prow][l15]      = f2bf(p0);
                Plds[wave][prow][16 + l15] = f2bf(p1);
            }
        }

        // ---- PV:  O += P @ V ----
        short8 vf[8];
        #pragma unroll
        for (int n = 0; n < 8; ++n)
            vf[n] = *(const short8*)&Vt[n * 16 + l15][lg * 8];
        #pragma unroll
        for (int mt = 0; mt < 2; ++mt) {
            short8 pf = *(const short8*)&Plds[wave][mt * 16 + l15][lg * 8];
            #pragma unroll
            for (int n = 0; n < 8; ++n)
                oacc[mt][n] = MFMA16(pf, vf[n], oacc[mt][n], 0, 0, 0);
        }
    }

    // ---- epilogue: normalize and store ----
    #pragma unroll
    for (int mt = 0; mt < 2; ++mt) {
        #pragma unroll
        for (int r = 0; r < 4; ++r) {
            float inv = 1.0f / lrun[mt][r];
            int qi = q0 + mt * 16 + lg * 4 + r;
            float* orow = outg + ((size_t)(qstart + qi) * HQN + hq) * HD + l15;
            #pragma unroll
            for (int n = 0; n < 8; ++n)
                orow[n * 16] = oacc[mt][n][r] * inv;
        }
    }
}

extern "C" void kernel_launch(void* const* d_in, const int* in_sizes, int n_in,
                              void* d_out, int out_size, void* d_ws, size_t ws_size,
                              hipStream_t stream) {
    const float* q  = (const float*)d_in[0];
    const float* k  = (const float*)d_in[1];
    const float* v  = (const float*)d_in[2];
    const int* bt   = (const int*)d_in[3];
    const int* sl   = (const int*)d_in[4];
    const int* qs   = (const int*)d_in[5];
    float* out      = (float*)d_out;

    dim3 grid(LQ_TOK / QB, HKVN, NSEQ);
    attn_fwd<<<grid, 256, 0, stream>>>(q, k, v, bt, sl, qs, out);
}

// Round 3
// 120.570 us; speedup vs baseline: 1.2880x; 1.2880x over previous
//
#include <hip/hip_runtime.h>
#include <stdint.h>

typedef __attribute__((ext_vector_type(8))) short short8;
typedef __attribute__((ext_vector_type(4))) float floatx4;
typedef __attribute__((ext_vector_type(4))) unsigned int uint4v;

#define NSEQ 8
#define BLKSZ 16
#define NBLK_PER_SEQ 128
#define HQN 32
#define HKVN 8
#define GQ 4
#define HD 128
#define WINDOW 1024
#define SCALE 0.08838834764831845f

#define QB 32       // q rows per block (4 waves = 4 GQA heads share K/V)
#define KVB 64      // kv tile
#define KROW 136    // K lds row stride (bf16): rows 272B -> 16B-aligned, uniform banks
#define VROW 72     // V^T lds row stride: rows 144B -> 16B-aligned
#define PROW 72     // P lds row stride

#define MFMA16 __builtin_amdgcn_mfma_f32_16x16x32_bf16

// two f32 -> packed bf16x2 (round-half-up) via one v_perm
static __device__ __forceinline__ unsigned int pack2bf(float lo, float hi) {
    unsigned int a = __builtin_bit_cast(unsigned int, lo) + 0x8000u;
    unsigned int b = __builtin_bit_cast(unsigned int, hi) + 0x8000u;
    return __builtin_amdgcn_perm(b, a, 0x07060302u);  // low16 = lo>>16, high16 = hi>>16
}
static __device__ __forceinline__ short f2bf(float x) {
    return (short)((__builtin_bit_cast(unsigned int, x) + 0x8000u) >> 16);
}

__global__ __launch_bounds__(256, 2)
void attn_fwd(const float* __restrict__ qg,
              const float* __restrict__ kg,
              const float* __restrict__ vg,
              const int* __restrict__ bt,
              const int* __restrict__ seqlens,
              const int* __restrict__ qsl,
              float* __restrict__ outg)
{
    __shared__ __align__(16) short Klds[KVB][KROW];   // 17408 B
    __shared__ __align__(16) short Vt[HD][VROW];      // 18432 B
    __shared__ __align__(16) short Plds[4][QB][PROW]; // 18432 B

    const int tid  = threadIdx.x;
    const int wave = tid >> 6;
    const int lane = tid & 63;
    const int l15  = lane & 15;
    const int lg   = lane >> 4;

    // XCD pinning: consecutive block ids round-robin XCDs -> b&7 = kv head
    const int b  = blockIdx.x;
    const int h  = b & 7;
    const int qt = (b >> 3) & 7;
    const int s  = b >> 6;
    const int q0 = qt * QB;

    const int qstart = qsl[s];
    const int numq   = qsl[s + 1] - qstart;
    const int slen   = seqlens[s];
    const int ctx    = slen - numq;
    const int hq     = h * GQ + wave;

    // ---- Q fragments (A-operand), pre-scaled by SCALE ----
    short8 qf[2][4];
    #pragma unroll
    for (int mt = 0; mt < 2; ++mt) {
        const float* qrow = qg + ((size_t)(qstart + q0 + mt * 16 + l15) * HQN + hq) * HD;
        #pragma unroll
        for (int kt = 0; kt < 4; ++kt) {
            floatx4 f0 = *(const floatx4*)(qrow + kt * 32 + lg * 8);
            floatx4 f1 = *(const floatx4*)(qrow + kt * 32 + lg * 8 + 4);
            uint4v w;
            w[0] = pack2bf(f0[0] * SCALE, f0[1] * SCALE);
            w[1] = pack2bf(f0[2] * SCALE, f0[3] * SCALE);
            w[2] = pack2bf(f1[0] * SCALE, f1[1] * SCALE);
            w[3] = pack2bf(f1[2] * SCALE, f1[3] * SCALE);
            qf[mt][kt] = __builtin_bit_cast(short8, w);
        }
    }

    floatx4 oacc[2][8];
    #pragma unroll
    for (int mt = 0; mt < 2; ++mt)
        #pragma unroll
        for (int n = 0; n < 8; ++n)
            oacc[mt][n] = (floatx4){0.f, 0.f, 0.f, 0.f};

    float mrun[2][4], lrun[2][4];
    #pragma unroll
    for (int mt = 0; mt < 2; ++mt)
        #pragma unroll
        for (int r = 0; r < 4; ++r) { mrun[mt][r] = -INFINITY; lrun[mt][r] = 0.f; }

    int lo = ctx + q0 - WINDOW + 1; if (lo < 0) lo = 0;
    int hi = ctx + q0 + QB - 1;     if (hi > slen - 1) hi = slen - 1;
    const int t0 = lo / KVB, t1 = hi / KVB;

    // staging maps
    const int srow = tid >> 3;          // K: kv row (0..31, +32 for p=1)
    const int sd0  = (tid & 7) * 16;    // K: d offset
    const int k2   = tid & 31;          // V: kv pair index (rows 2k2, 2k2+1)
    const int d0v  = (tid >> 5) * 16;   // V: d offset

    floatx4 fk[8], fv[8];   // raw f32 for next tile (T14 async split)

    // prologue: load tile t0
    {
        const int kv0 = t0 * KVB;
        #pragma unroll
        for (int p = 0; p < 2; ++p) {
            const int kvp = kv0 + p * 32 + srow;
            const int blk = bt[s * NBLK_PER_SEQ + (kvp >> 4)];
            const float* src = kg + (((size_t)blk * BLKSZ + (kvp & 15)) * HKVN + h) * HD + sd0;
            fk[p*4+0] = *(const floatx4*)(src);
            fk[p*4+1] = *(const floatx4*)(src + 4);
            fk[p*4+2] = *(const floatx4*)(src + 8);
            fk[p*4+3] = *(const floatx4*)(src + 12);
        }
        const int kvv = kv0 + 2 * k2;
        const int blk = bt[s * NBLK_PER_SEQ + (kvv >> 4)];   // kvv even -> kvv+1 same block
        const float* src = vg + (((size_t)blk * BLKSZ + (kvv & 15)) * HKVN + h) * HD + d0v;
        #pragma unroll
        for (int j = 0; j < 4; ++j) {
            fv[j]     = *(const floatx4*)(src + j * 4);
            fv[4 + j] = *(const floatx4*)(src + (size_t)HKVN * HD + j * 4);
        }
    }

    for (int t = t0; t <= t1; ++t) {
        const int kv0 = t * KVB;
        __syncthreads();   // all waves done with previous tile's LDS

        // ---- convert + store tile t (K row-major, V^T with kv-paired b32) ----
        #pragma unroll
        for (int p = 0; p < 2; ++p) {
            const int row = p * 32 + srow;
            uint4v w;
            w[0] = pack2bf(fk[p*4+0][0], fk[p*4+0][1]);
            w[1] = pack2bf(fk[p*4+0][2], fk[p*4+0][3]);
            w[2] = pack2bf(fk[p*4+1][0], fk[p*4+1][1]);
            w[3] = pack2bf(fk[p*4+1][2], fk[p*4+1][3]);
            *(uint4v*)&Klds[row][sd0] = w;
            w[0] = pack2bf(fk[p*4+2][0], fk[p*4+2][1]);
            w[1] = pack2bf(fk[p*4+2][2], fk[p*4+2][3]);
            w[2] = pack2bf(fk[p*4+3][0], fk[p*4+3][1]);
            w[3] = pack2bf(fk[p*4+3][2], fk[p*4+3][3]);
            *(uint4v*)&Klds[row][sd0 + 8] = w;
        }
        #pragma unroll
        for (int i = 0; i < 16; ++i) {
            // low short = even kv, high = odd kv
            *(unsigned int*)&Vt[d0v + i][2 * k2] =
                pack2bf(fv[i >> 2][i & 3], fv[4 + (i >> 2)][i & 3]);
        }
        __syncthreads();

        // ---- QK^T: S[q][kv] ----
        floatx4 sacc[2][4];
        #pragma unroll
        for (int mt = 0; mt < 2; ++mt)
            #pragma unroll
            for (int nt = 0; nt < 4; ++nt)
                sacc[mt][nt] = (floatx4){0.f, 0.f, 0.f, 0.f};
        #pragma unroll
        for (int kt = 0; kt < 4; ++kt) {
            #pragma unroll
            for (int nt = 0; nt < 4; ++nt) {
                short8 kf = *(const short8*)&Klds[nt * 16 + l15][kt * 32 + lg * 8];
                sacc[0][nt] = MFMA16(qf[0][kt], kf, sacc[0][nt], 0, 0, 0);
                sacc[1][nt] = MFMA16(qf[1][kt], kf, sacc[1][nt], 0, 0, 0);
            }
        }

        // ---- issue next tile's global loads (overlap with softmax+PV) ----
        if (t < t1) {
            const int kv0n = kv0 + KVB;
            #pragma unroll
            for (int p = 0; p < 2; ++p) {
                const int kvp = kv0n + p * 32 + srow;
                const int blk = bt[s * NBLK_PER_SEQ + (kvp >> 4)];
                const float* src = kg + (((size_t)blk * BLKSZ + (kvp & 15)) * HKVN + h) * HD + sd0;
                fk[p*4+0] = *(const floatx4*)(src);
                fk[p*4+1] = *(const floatx4*)(src + 4);
                fk[p*4+2] = *(const floatx4*)(src + 8);
                fk[p*4+3] = *(const floatx4*)(src + 12);
            }
            const int kvv = kv0n + 2 * k2;
            const int blk = bt[s * NBLK_PER_SEQ + (kvv >> 4)];
            const float* src = vg + (((size_t)blk * BLKSZ + (kvv & 15)) * HKVN + h) * HD + d0v;
            #pragma unroll
            for (int j = 0; j < 4; ++j) {
                fv[j]     = *(const floatx4*)(src + j * 4);
                fv[4 + j] = *(const floatx4*)(src + (size_t)HKVN * HD + j * 4);
            }
        }

        // ---- online softmax (per q-row), interior fast path + defer-max ----
        const bool interior = (kv0 >= ctx + q0 - (WINDOW - QB)) &&
                              (kv0 + KVB - 1 <= ctx + q0);
        #pragma unroll
        for (int mt = 0; mt < 2; ++mt) {
            #pragma unroll
            for (int r = 0; r < 4; ++r) {
                float sv[4];
                if (interior) {
                    #pragma unroll
                    for (int nt = 0; nt < 4; ++nt) sv[nt] = sacc[mt][nt][r];
                } else {
                    const int qpos = ctx + q0 + mt * 16 + lg * 4 + r;
                    #pragma unroll
                    for (int nt = 0; nt < 4; ++nt) {
                        const int kpos = kv0 + nt * 16 + l15;
                        const bool valid = (kpos <= qpos) && (qpos - kpos < WINDOW);
                        sv[nt] = valid ? sacc[mt][nt][r] : -INFINITY;
                    }
                }
                float rmax = fmaxf(fmaxf(sv[0], sv[1]), fmaxf(sv[2], sv[3]));
                rmax = fmaxf(rmax, __shfl_xor(rmax, 1));
                rmax = fmaxf(rmax, __shfl_xor(rmax, 2));
                rmax = fmaxf(rmax, __shfl_xor(rmax, 4));
                rmax = fmaxf(rmax, __shfl_xor(rmax, 8));
                const float mold = mrun[mt][r];
                const bool defer = __all(rmax <= mold + 8.0f);
                const float mnew = defer ? mold : fmaxf(mold, rmax);
                const float alpha = defer ? 1.0f
                    : ((mnew == -INFINITY) ? 1.0f : __expf(mold - mnew));
                const bool dead = (mnew == -INFINITY);
                float e[4], rsum = 0.f;
                #pragma unroll
                for (int nt = 0; nt < 4; ++nt) {
                    e[nt] = dead ? 0.f : __expf(sv[nt] - mnew);
                    rsum += e[nt];
                }
                rsum += __shfl_xor(rsum, 1);
                rsum += __shfl_xor(rsum, 2);
                rsum += __shfl_xor(rsum, 4);
                rsum += __shfl_xor(rsum, 8);
                lrun[mt][r] = lrun[mt][r] * alpha + rsum;
                mrun[mt][r] = mnew;
                if (alpha != 1.0f) {
                    #pragma unroll
                    for (int n = 0; n < 8; ++n) oacc[mt][n][r] *= alpha;
                }
                const int prow = mt * 16 + lg * 4 + r;
                #pragma unroll
                for (int nt = 0; nt < 4; ++nt)
                    Plds[wave][prow][nt * 16 + l15] = f2bf(e[nt]);
            }
        }

        // ---- PV: O += P @ V  (A = P from own-wave Plds, B = V^T rows) ----
        #pragma unroll
        for (int ks = 0; ks < 2; ++ks) {
            short8 pf0 = *(const short8*)&Plds[wave][l15     ][ks * 32 + lg * 8];
            short8 pf1 = *(const short8*)&Plds[wave][16 + l15][ks * 32 + lg * 8];
            #pragma unroll
            for (int n = 0; n < 8; ++n) {
                short8 vfn = *(const short8*)&Vt[n * 16 + l15][ks * 32 + lg * 8];
                oacc[0][n] = MFMA16(pf0, vfn, oacc[0][n], 0, 0, 0);
                oacc[1][n] = MFMA16(pf1, vfn, oacc[1][n], 0, 0, 0);
            }
        }
    }

    // ---- epilogue ----
    #pragma unroll
    for (int mt = 0; mt < 2; ++mt) {
        #pragma unroll
        for (int r = 0; r < 4; ++r) {
            const float inv = 1.0f / lrun[mt][r];
            const int qi = q0 + mt * 16 + lg * 4 + r;
            float* orow = outg + ((size_t)(qstart + qi) * HQN + hq) * HD + l15;
            #pragma unroll
            for (int n = 0; n < 8; ++n)
                orow[n * 16] = oacc[mt][n][r] * inv;
        }
    }
}

extern "C" void kernel_launch(void* const* d_in, const int* in_sizes, int n_in,
                              void* d_out, int out_size, void* d_ws, size_t ws_size,
                              hipStream_t stream) {
    const float* q  = (const float*)d_in[0];
    const float* k  = (const float*)d_in[1];
    const float* v  = (const float*)d_in[2];
    const int* btp  = (const int*)d_in[3];
    const int* sl   = (const int*)d_in[4];
    const int* qs   = (const int*)d_in[5];
    float* out      = (float*)d_out;

    attn_fwd<<<dim3(NSEQ * HKVN * 8), 256, 0, stream>>>(q, k, v, btp, sl, qs, out);
}